// Round 1
// baseline (968.029 us; speedup 1.0000x reference)
//
#include <hip/hip_runtime.h>
#include <hip/hip_cooperative_groups.h>
#include <math.h>

namespace cg = cooperative_groups;

#define R_TOT 8192
#define CORE  4915
#define SHELL 2457
#define FB    820
#define H     1024

#define NBLK  1024   // exactly 4 blocks/CU * 256 CUs (LDS-limited capacity)
#define NTHR  256

// Device-global scratch (fully rewritten every launch before any read).
__device__ __align__(16) float g_pred1[R_TOT];
__device__ __align__(16) float g_s[R_TOT];
__device__ __align__(16) float g_gates[4 * H];
__device__ int g_q1 = 0;  // reset in-kernel after phase 1
__device__ int g_q2 = 0;  // reset in-kernel after phase 2

// LDS swizzle: i -> i + i/32. Turns the stride-4-floats-per-lane read pattern
// (8-way bank conflict) into 2 lanes/bank (free per m136).
__device__ __forceinline__ int swz(int i) { return i + (i >> 5); }
#define SWZ_SIZE(n) ((n) + (((n) - 1) >> 5))

__device__ __forceinline__ float waveReduce(float v) {
  #pragma unroll
  for (int off = 32; off; off >>= 1) v += __shfl_down(v, off, 64);
  return v;
}

__device__ __forceinline__ float sigm(float x) { return 1.f / (1.f + expf(-x)); }

// Dot of one f32 weight row (4B-aligned, arbitrary 16B phase) against x staged
// swizzled in LDS (logical x[j] at xs[swz(xb + j)]).
// 16B-aligned float4 main loop, manually unrolled x4 with independent
// accumulators -> 4 global loads in flight per wave.
__device__ __forceinline__ float dotRow(const float* __restrict__ w,
                                        const float* __restrict__ xs,
                                        int xb, int N, int lane) {
  uintptr_t a = (uintptr_t)w;
  int head = (int)(((16 - (a & 15)) & 15) >> 2);  // elements until 16B aligned
  if (head > N) head = N;
  float s0 = 0.f, s1 = 0.f, s2 = 0.f, s3 = 0.f;
  if (lane < head) s0 += w[lane] * xs[swz(xb + lane)];
  int nC = (N - head) >> 2;
  const float4* wv = (const float4*)(w + head);
  int b0 = xb + head;
  int c = lane;
  for (; c + 192 < nC; c += 256) {
    float4 v0 = wv[c], v1 = wv[c + 64], v2 = wv[c + 128], v3 = wv[c + 192];
    int i0 = b0 + (c << 2);
    s0 += v0.x*xs[swz(i0    )] + v0.y*xs[swz(i0+  1)] + v0.z*xs[swz(i0+  2)] + v0.w*xs[swz(i0+  3)];
    s1 += v1.x*xs[swz(i0+256)] + v1.y*xs[swz(i0+257)] + v1.z*xs[swz(i0+258)] + v1.w*xs[swz(i0+259)];
    s2 += v2.x*xs[swz(i0+512)] + v2.y*xs[swz(i0+513)] + v2.z*xs[swz(i0+514)] + v2.w*xs[swz(i0+515)];
    s3 += v3.x*xs[swz(i0+768)] + v3.y*xs[swz(i0+769)] + v3.z*xs[swz(i0+770)] + v3.w*xs[swz(i0+771)];
  }
  for (; c < nC; c += 64) {
    float4 v = wv[c];
    int i0 = b0 + (c << 2);
    s1 += v.x*xs[swz(i0)] + v.y*xs[swz(i0+1)] + v.z*xs[swz(i0+2)] + v.w*xs[swz(i0+3)];
  }
  for (int i = head + (nC << 2) + lane; i < N; i += 64)
    s2 += w[i] * xs[swz(xb + i)];
  return (s0 + s1) + (s2 + s3);
}

__device__ __forceinline__ void s_update(int i, float pred,
                                         const float* __restrict__ state,
                                         const float* __restrict__ omega,
                                         const float* __restrict__ gamma,
                                         float dopa, float* __restrict__ dout) {
  float old = state[i];
  float s1 = 0.9f * old + 0.1f * pred;
  float s2 = s1 + 0.1f * (omega[i] * s1 - gamma[i] * tanhf(s1));
  float s3 = dopa * s2;
  g_s[i] = s3;
  dout[1 + i] = s3;  // s occupies output elements [1, 1+R_TOT)
}

// ---------------- Fused cooperative kernel -----------------------------------
// Phase-1 task queue, LPT order: core rows (len 4915), shell (2457),
// W_hh rows (1024, dependency-free -> overlapped here), fb (820).
#define P1_SHELL0 CORE
#define P1_WHH0   (CORE + SHELL)
#define P1_FB0    (CORE + SHELL + 4 * H)
#define P1_N      (CORE + SHELL + 4 * H + FB)

__global__ __launch_bounds__(NTHR, 4) void k_fused(
    const float* __restrict__ state, const float* __restrict__ Wcore,
    const float* __restrict__ Wshell, const float* __restrict__ Wfb,
    const float* __restrict__ Win, const float* __restrict__ xin,
    const float* __restrict__ Wsc, const float* __restrict__ Wfc,
    const float* __restrict__ omega, const float* __restrict__ gamma,
    const float* __restrict__ dopamine,
    const float* __restrict__ Wih, const float* __restrict__ Whh,
    const float* __restrict__ bih, const float* __restrict__ bhh,
    const float* __restrict__ hin, const float* __restrict__ cin,
    const float* __restrict__ Wout, const float* __restrict__ bout,
    float* __restrict__ dout) {
  __shared__ float xs[SWZ_SIZE(R_TOT + H)];  // 38,012 B -> 4 blocks/CU
  __shared__ float red[4];
  cg::grid_group grid = cg::this_grid();
  const int tid = threadIdx.x, wave = tid >> 6, lane = tid & 63;

  // ---------- Phase 1: pred matvecs + W_hh@h partial gates ----------
  {
    const float4* s4 = (const float4*)state;
    for (int i = tid; i < R_TOT / 4; i += NTHR) {
      float4 v = s4[i]; int b = i << 2;
      xs[swz(b)] = v.x; xs[swz(b+1)] = v.y; xs[swz(b+2)] = v.z; xs[swz(b+3)] = v.w;
    }
    const float4* h4 = (const float4*)hin;
    for (int i = tid; i < H / 4; i += NTHR) {
      float4 v = h4[i]; int b = R_TOT + (i << 2);
      xs[swz(b)] = v.x; xs[swz(b+1)] = v.y; xs[swz(b+2)] = v.z; xs[swz(b+3)] = v.w;
    }
  }
  __syncthreads();
  const float x0 = xin[0];

  for (;;) {
    int idx;
    if (lane == 0) idx = atomicAdd(&g_q1, 1);
    idx = __shfl(idx, 0, 64);
    if (idx >= P1_N) break;
    const float* w; int xb, N; float* dst; float pre = 0.f; int doT = 1;
    if (idx < P1_SHELL0) {
      w = Wcore + (size_t)idx * CORE; xb = 0; N = CORE;
      dst = g_pred1 + idx; pre = Win[idx] * x0;
    } else if (idx < P1_WHH0) {
      int r = idx - P1_SHELL0;
      w = Wshell + (size_t)r * SHELL; xb = CORE; N = SHELL;
      dst = g_pred1 + CORE + r;
    } else if (idx < P1_FB0) {
      int r = idx - P1_WHH0;
      w = Whh + (size_t)r * H; xb = R_TOT; N = H;
      dst = g_gates + r; doT = 0;  // raw partial, biases added in phase 3
    } else {
      int r = idx - P1_FB0;
      w = Wfb + (size_t)r * FB; xb = CORE + SHELL; N = FB;
      dst = g_pred1 + CORE + SHELL + r;
    }
    float sum = waveReduce(dotRow(w, xs, xb, N, lane)) + pre;
    if (lane == 0) *dst = doT ? tanhf(sum) : sum;
  }

  grid.sync();

  // ---------- Phase 2: core cross-terms + full s update ----------
  if (blockIdx.x == 0 && tid == 0) atomicExch(&g_q1, 0);  // ready for next launch
  const float dopa = dopamine[0];
  {
    int gt = blockIdx.x * NTHR + tid;  // elementwise shell+fb update
    if (gt < SHELL + FB) {
      int i = CORE + gt;
      s_update(i, g_pred1[i], state, omega, gamma, dopa, dout);
    }
  }
  for (int i = tid; i < SHELL + FB; i += NTHR) xs[swz(i)] = g_pred1[CORE + i];
  __syncthreads();
  for (;;) {
    int idx;
    if (lane == 0) idx = atomicAdd(&g_q2, 1);
    idx = __shfl(idx, 0, 64);
    if (idx >= CORE) break;
    float d1 = waveReduce(dotRow(Wsc + (size_t)idx * SHELL, xs, 0, SHELL, lane));
    float d2 = waveReduce(dotRow(Wfc + (size_t)idx * FB, xs, SHELL, FB, lane));
    if (lane == 0) {
      float pred = g_pred1[idx] + tanhf(d1) + tanhf(d2);
      s_update(idx, pred, state, omega, gamma, dopa, dout);
    }
  }

  grid.sync();

  // ---------- Phase 3: gates += W_ih @ s + biases ----------
  if (blockIdx.x == 0 && tid == 0) atomicExch(&g_q2, 0);
  {
    const float4* s4 = (const float4*)g_s;
    for (int i = tid; i < R_TOT / 4; i += NTHR) {
      float4 v = s4[i]; int b = i << 2;
      xs[swz(b)] = v.x; xs[swz(b+1)] = v.y; xs[swz(b+2)] = v.z; xs[swz(b+3)] = v.w;
    }
  }
  __syncthreads();
  {
    int r = blockIdx.x * 4 + wave;  // 4096 rows over 4096 waves, exactly 1 each
    float sum = waveReduce(dotRow(Wih + (size_t)r * R_TOT, xs, 0, R_TOT, lane));
    if (lane == 0) g_gates[r] += sum + bih[r] + bhh[r];
  }

  grid.sync();

  // ---------- Phase 4: LSTM elementwise + output dot (block 0) ----------
  if (blockIdx.x == 0) {
    float acc = 0.f;
    for (int j = tid; j < H; j += NTHR) {
      float ig = g_gates[j], fg = g_gates[H + j];
      float gg = g_gates[2 * H + j], og = g_gates[3 * H + j];
      float c = cin[j];
      float cn = sigm(fg) * c + sigm(ig) * tanhf(gg);
      float hn = sigm(og) * tanhf(cn);
      dout[1 + R_TOT + j] = hn;
      dout[1 + R_TOT + H + j] = cn;
      acc += Wout[j] * hn;
    }
    acc = waveReduce(acc);
    if (lane == 0) red[wave] = acc;
    __syncthreads();
    if (tid == 0) dout[0] = red[0] + red[1] + red[2] + red[3] + bout[0];
  }
}

// ================= Fallback: previous verified 4-kernel pipeline =============
#define NB1_CORE  ((CORE  + 3) / 4)
#define NB1_SHELL ((SHELL + 3) / 4)
#define NB1_FB    ((FB    + 3) / 4)

__global__ __launch_bounds__(256, 8) void k_stage1(
    const float* __restrict__ state, const float* __restrict__ Wcore,
    const float* __restrict__ Wshell, const float* __restrict__ Wfb,
    const float* __restrict__ Win, const float* __restrict__ xin) {
  __shared__ float xs[SWZ_SIZE(CORE)];
  int b = blockIdx.x;
  int rowBase, N, xoff, isCore = 0;
  const float* W;
  if (b < NB1_CORE)                  { rowBase = b * 4;                         N = CORE;  xoff = 0;            W = Wcore; isCore = 1; }
  else if (b < NB1_CORE + NB1_SHELL) { rowBase = (b - NB1_CORE) * 4;            N = SHELL; xoff = CORE;         W = Wshell; }
  else                               { rowBase = (b - NB1_CORE - NB1_SHELL)*4;  N = FB;    xoff = CORE + SHELL; W = Wfb; }
  for (int i = threadIdx.x; i < N; i += 256) xs[swz(i)] = state[xoff + i];
  __syncthreads();
  int wave = threadIdx.x >> 6, lane = threadIdx.x & 63;
  int r = rowBase + wave;
  if (r >= N) return;
  float sum = waveReduce(dotRow(W + (size_t)r * N, xs, 0, N, lane));
  if (lane == 0) {
    if (isCore) sum += Win[r] * xin[0];
    g_pred1[xoff + r] = tanhf(sum);
  }
}

#define NB2_CORE ((CORE + 3) / 4)
#define NB2_EW   ((SHELL + FB + 255) / 256)

__global__ __launch_bounds__(256, 8) void k_stage2(
    const float* __restrict__ state,
    const float* __restrict__ Wsc, const float* __restrict__ Wfc,
    const float* __restrict__ omega, const float* __restrict__ gamma,
    const float* __restrict__ dopamine, float* __restrict__ dout) {
  __shared__ float xs[SWZ_SIZE(SHELL + FB)];
  float dopa = dopamine[0];
  int b = blockIdx.x;
  if (b < NB2_CORE) {
    for (int i = threadIdx.x; i < SHELL + FB; i += 256) xs[swz(i)] = g_pred1[CORE + i];
    __syncthreads();
    int wave = threadIdx.x >> 6, lane = threadIdx.x & 63;
    int r = b * 4 + wave;
    if (r >= CORE) return;
    float d1 = waveReduce(dotRow(Wsc + (size_t)r * SHELL, xs, 0, SHELL, lane));
    float d2 = waveReduce(dotRow(Wfc + (size_t)r * FB, xs, SHELL, FB, lane));
    if (lane == 0) {
      float pred = g_pred1[r] + tanhf(d1) + tanhf(d2);
      s_update(r, pred, state, omega, gamma, dopa, dout);
    }
  } else {
    int i = CORE + (b - NB2_CORE) * 256 + threadIdx.x;
    if (i < R_TOT) s_update(i, g_pred1[i], state, omega, gamma, dopa, dout);
  }
}

__global__ __launch_bounds__(256, 4) void k_gates(
    const float* __restrict__ h,
    const float* __restrict__ Wih, const float* __restrict__ Whh,
    const float* __restrict__ bih, const float* __restrict__ bhh) {
  __shared__ float xs[SWZ_SIZE(R_TOT + H)];
  for (int i = threadIdx.x; i < R_TOT; i += 256) xs[swz(i)] = g_s[i];
  for (int i = threadIdx.x; i < H; i += 256) xs[swz(R_TOT + i)] = h[i];
  __syncthreads();
  int wave = threadIdx.x >> 6, lane = threadIdx.x & 63;
  int r = blockIdx.x * 4 + wave;
  float sum = dotRow(Wih + (size_t)r * R_TOT, xs, 0, R_TOT, lane)
            + dotRow(Whh + (size_t)r * H, xs, R_TOT, H, lane);
  sum = waveReduce(sum);
  if (lane == 0) g_gates[r] = sum + bih[r] + bhh[r];
}

__global__ __launch_bounds__(1024) void k_lstm(
    const float* __restrict__ c_in, const float* __restrict__ Wout,
    const float* __restrict__ bout, float* __restrict__ dout) {
  __shared__ float red16[16];
  int j = threadIdx.x;
  float ig = g_gates[j], fg = g_gates[H + j], gg = g_gates[2 * H + j], og = g_gates[3 * H + j];
  float c = c_in[j];
  float cn = sigm(fg) * c + sigm(ig) * tanhf(gg);
  float hn = sigm(og) * tanhf(cn);
  dout[1 + R_TOT + j] = hn;
  dout[1 + R_TOT + H + j] = cn;
  float w = Wout[j] * hn;
  w = waveReduce(w);
  int wave = j >> 6, lane = j & 63;
  if (lane == 0) red16[wave] = w;
  __syncthreads();
  if (j == 0) {
    float t = 0.f;
    #pragma unroll
    for (int k = 0; k < 16; ++k) t += red16[k];
    dout[0] = t + bout[0];
  }
}

extern "C" void kernel_launch(void* const* d_in, const int* in_sizes, int n_in,
                              void* d_out, int out_size, void* d_ws, size_t ws_size,
                              hipStream_t stream) {
  // Map inputs by element-count fingerprint (confirmed f32).
  const float *x = 0, *state = 0, *h = 0, *c = 0, *Win = 0, *Wcore = 0, *Wshell = 0,
              *Wfb = 0, *Wsc = 0, *Wfc = 0, *dopa = 0, *omega = 0, *gamma = 0,
              *Wih = 0, *Whh = 0, *bih = 0, *bhh = 0, *Wout = 0, *bout = 0;
  int n1 = 0, n1024 = 0, n8192 = 0, n4096 = 0;
  for (int i = 0; i < n_in; ++i) {
    const float* p = (const float*)d_in[i];
    switch (in_sizes[i]) {
      case 24157225: Wcore = p; break;            // CORE^2
      case 6036849:  Wshell = p; break;           // SHELL^2
      case 672400:   Wfb = p; break;              // FB^2
      case 12076155: Wsc = p; break;              // CORE*SHELL
      case 4030300:  Wfc = p; break;              // CORE*FB
      case 33554432: Wih = p; break;              // 4H*R
      case 4194304:  Whh = p; break;              // 4H*H
      case 1:    { if (n1 == 0) x = p; else if (n1 == 1) dopa = p; else bout = p; n1++; } break;
      case 1024: { if (n1024 == 0) h = p; else if (n1024 == 1) c = p; else Wout = p; n1024++; } break;
      case 8192: { if (n8192 == 0) state = p; else if (n8192 == 1) Win = p;
                   else if (n8192 == 2) omega = p; else gamma = p; n8192++; } break;
      case 4096: { if (n4096 == 0) bih = p; else bhh = p; n4096++; } break;
      default: break;
    }
  }
  float* dout = (float*)d_out;

  void* args[] = {(void*)&state, (void*)&Wcore, (void*)&Wshell, (void*)&Wfb,
                  (void*)&Win, (void*)&x, (void*)&Wsc, (void*)&Wfc,
                  (void*)&omega, (void*)&gamma, (void*)&dopa,
                  (void*)&Wih, (void*)&Whh, (void*)&bih, (void*)&bhh,
                  (void*)&h, (void*)&c, (void*)&Wout, (void*)&bout, (void*)&dout};
  hipError_t e = hipLaunchCooperativeKernel((void*)k_fused, dim3(NBLK), dim3(NTHR),
                                            args, 0, stream);
  if (e != hipSuccess) {
    (void)hipGetLastError();  // clear sticky error; run verified 4-kernel path
    k_stage1<<<NB1_CORE + NB1_SHELL + NB1_FB, 256, 0, stream>>>(
        state, Wcore, Wshell, Wfb, Win, x);
    k_stage2<<<NB2_CORE + NB2_EW, 256, 0, stream>>>(
        state, Wsc, Wfc, omega, gamma, dopa, dout);
    k_gates<<<(4 * H) / 4, 256, 0, stream>>>(h, Wih, Whh, bih, bhh);
    k_lstm<<<1, 1024, 0, stream>>>(c, Wout, bout, dout);
  }
}

// Round 2
// 367.025 us; speedup vs baseline: 2.6375x; 2.6375x over previous
//
#include <hip/hip_runtime.h>
#include <math.h>

#define R_TOT 8192
#define CORE  4915
#define SHELL 2457
#define FB    820
#define H     1024

// Device-global scratch (fully rewritten every launch before any read).
__device__ __align__(16) float g_pred1[R_TOT];
__device__ __align__(16) float g_s[R_TOT];
__device__ __align__(16) float g_gates[4 * H];

// LDS swizzle for the misaligned scalar path: i -> i + i/32 (2 lanes/bank = free).
__device__ __forceinline__ int swz(int i) { return i + (i >> 5); }
#define SWZ_SIZE(n) ((n) + (((n) - 1) >> 5))

__device__ __forceinline__ float waveReduce(float v) {
  #pragma unroll
  for (int off = 32; off; off >>= 1) v += __shfl_down(v, off, 64);
  return v;
}

__device__ __forceinline__ float sigm(float x) { return 1.f / (1.f + expf(-x)); }
__device__ __forceinline__ float dot4(float4 a, float4 b) {
  return a.x * b.x + a.y * b.y + a.z * b.z + a.w * b.w;
}

// ---- Misaligned-row path: w 4B-aligned (arbitrary 16B phase), xs swizzled ----
// 8 independent float4 loads in flight per wave (latency hiding), then x4/x1 tiers.
__device__ __forceinline__ float dotRowSw(const float* __restrict__ w,
                                          const float* __restrict__ xs,
                                          int xb, int N, int lane) {
  uintptr_t a = (uintptr_t)w;
  int head = (int)(((16 - (a & 15)) & 15) >> 2);  // elements until 16B aligned
  if (head > N) head = N;
  float s0 = 0.f, s1 = 0.f, s2 = 0.f, s3 = 0.f,
        s4 = 0.f, s5 = 0.f, s6 = 0.f, s7 = 0.f;
  if (lane < head) s0 += w[lane] * xs[swz(xb + lane)];
  int nC = (N - head) >> 2;
  const float4* wv = (const float4*)(w + head);
  int b0 = xb + head;
  int c = lane;
  for (; c + 448 < nC; c += 512) {
    float4 v0 = wv[c],       v1 = wv[c + 64],  v2 = wv[c + 128], v3 = wv[c + 192],
           v4 = wv[c + 256], v5 = wv[c + 320], v6 = wv[c + 384], v7 = wv[c + 448];
    int i0 = b0 + (c << 2);
    s0 += v0.x*xs[swz(i0     )] + v0.y*xs[swz(i0+   1)] + v0.z*xs[swz(i0+   2)] + v0.w*xs[swz(i0+   3)];
    s1 += v1.x*xs[swz(i0+ 256)] + v1.y*xs[swz(i0+ 257)] + v1.z*xs[swz(i0+ 258)] + v1.w*xs[swz(i0+ 259)];
    s2 += v2.x*xs[swz(i0+ 512)] + v2.y*xs[swz(i0+ 513)] + v2.z*xs[swz(i0+ 514)] + v2.w*xs[swz(i0+ 515)];
    s3 += v3.x*xs[swz(i0+ 768)] + v3.y*xs[swz(i0+ 769)] + v3.z*xs[swz(i0+ 770)] + v3.w*xs[swz(i0+ 771)];
    s4 += v4.x*xs[swz(i0+1024)] + v4.y*xs[swz(i0+1025)] + v4.z*xs[swz(i0+1026)] + v4.w*xs[swz(i0+1027)];
    s5 += v5.x*xs[swz(i0+1280)] + v5.y*xs[swz(i0+1281)] + v5.z*xs[swz(i0+1282)] + v5.w*xs[swz(i0+1283)];
    s6 += v6.x*xs[swz(i0+1536)] + v6.y*xs[swz(i0+1537)] + v6.z*xs[swz(i0+1538)] + v6.w*xs[swz(i0+1539)];
    s7 += v7.x*xs[swz(i0+1792)] + v7.y*xs[swz(i0+1793)] + v7.z*xs[swz(i0+1794)] + v7.w*xs[swz(i0+1795)];
  }
  for (; c + 192 < nC; c += 256) {
    float4 v0 = wv[c], v1 = wv[c + 64], v2 = wv[c + 128], v3 = wv[c + 192];
    int i0 = b0 + (c << 2);
    s0 += v0.x*xs[swz(i0    )] + v0.y*xs[swz(i0+  1)] + v0.z*xs[swz(i0+  2)] + v0.w*xs[swz(i0+  3)];
    s1 += v1.x*xs[swz(i0+256)] + v1.y*xs[swz(i0+257)] + v1.z*xs[swz(i0+258)] + v1.w*xs[swz(i0+259)];
    s2 += v2.x*xs[swz(i0+512)] + v2.y*xs[swz(i0+513)] + v2.z*xs[swz(i0+514)] + v2.w*xs[swz(i0+515)];
    s3 += v3.x*xs[swz(i0+768)] + v3.y*xs[swz(i0+769)] + v3.z*xs[swz(i0+770)] + v3.w*xs[swz(i0+771)];
  }
  for (; c < nC; c += 64) {
    float4 v = wv[c];
    int i0 = b0 + (c << 2);
    s1 += v.x*xs[swz(i0)] + v.y*xs[swz(i0+1)] + v.z*xs[swz(i0+2)] + v.w*xs[swz(i0+3)];
  }
  for (int i = head + (nC << 2) + lane; i < N; i += 64)
    s2 += w[i] * xs[swz(xb + i)];
  return ((s0 + s1) + (s2 + s3)) + ((s4 + s5) + (s6 + s7));
}

// ---- Aligned-row path: w 16B-aligned, xs unswizzled float4 (ds_read_b128) ----
__device__ __forceinline__ float dotRowAl(const float4* __restrict__ wv,
                                          const float4* __restrict__ xs4,
                                          int nC, int lane) {
  float s0 = 0.f, s1 = 0.f, s2 = 0.f, s3 = 0.f,
        s4 = 0.f, s5 = 0.f, s6 = 0.f, s7 = 0.f;
  int c = lane;
  for (; c + 448 < nC; c += 512) {
    float4 v0 = wv[c],       v1 = wv[c + 64],  v2 = wv[c + 128], v3 = wv[c + 192],
           v4 = wv[c + 256], v5 = wv[c + 320], v6 = wv[c + 384], v7 = wv[c + 448];
    s0 += dot4(v0, xs4[c      ]); s1 += dot4(v1, xs4[c + 64 ]);
    s2 += dot4(v2, xs4[c + 128]); s3 += dot4(v3, xs4[c + 192]);
    s4 += dot4(v4, xs4[c + 256]); s5 += dot4(v5, xs4[c + 320]);
    s6 += dot4(v6, xs4[c + 384]); s7 += dot4(v7, xs4[c + 448]);
  }
  for (; c + 192 < nC; c += 256) {
    float4 v0 = wv[c], v1 = wv[c + 64], v2 = wv[c + 128], v3 = wv[c + 192];
    s0 += dot4(v0, xs4[c      ]); s1 += dot4(v1, xs4[c + 64 ]);
    s2 += dot4(v2, xs4[c + 128]); s3 += dot4(v3, xs4[c + 192]);
  }
  for (; c < nC; c += 64) s1 += dot4(wv[c], xs4[c]);
  return ((s0 + s1) + (s2 + s3)) + ((s4 + s5) + (s6 + s7));
}

__device__ __forceinline__ void s_update(int i, float pred,
                                         const float* __restrict__ state,
                                         const float* __restrict__ omega,
                                         const float* __restrict__ gamma,
                                         float dopa, float* __restrict__ dout) {
  float old = state[i];
  float s1 = 0.9f * old + 0.1f * pred;
  float s2 = s1 + 0.1f * (omega[i] * s1 - gamma[i] * tanhf(s1));
  float s3 = dopa * s2;
  g_s[i] = s3;
  dout[1 + i] = s3;  // s occupies output elements [1, 1+R_TOT)
}

// ---------------- Stage 1: core/shell/fb matvecs + W_hh@h partial gates -----
#define NB1_CORE  ((CORE  + 3) / 4)   // 1229
#define NB1_SHELL ((SHELL + 3) / 4)   // 615
#define NB1_WHH   (4 * H / 4)         // 1024 (4096 rows, 4 per block)
#define NB1_FB    ((FB    + 3) / 4)   // 205
#define NB1_TOT   (NB1_CORE + NB1_SHELL + NB1_WHH + NB1_FB)

__global__ __launch_bounds__(256, 4) void k_stage1(
    const float* __restrict__ state, const float* __restrict__ Wcore,
    const float* __restrict__ Wshell, const float* __restrict__ Wfb,
    const float* __restrict__ Win, const float* __restrict__ xin,
    const float* __restrict__ Whh, const float* __restrict__ hin) {
  __shared__ __align__(16) float xs[SWZ_SIZE(CORE)];  // 20,272 B
  int b = blockIdx.x;
  int tid = threadIdx.x, wave = tid >> 6, lane = tid & 63;
  if (b < NB1_CORE) {
    for (int i = tid; i < CORE; i += 256) xs[swz(i)] = state[i];
    __syncthreads();
    int r = b * 4 + wave;
    if (r >= CORE) return;
    float sum = waveReduce(dotRowSw(Wcore + (size_t)r * CORE, xs, 0, CORE, lane));
    if (lane == 0) g_pred1[r] = tanhf(sum + Win[r] * xin[0]);
  } else if (b < NB1_CORE + NB1_SHELL) {
    for (int i = tid; i < SHELL; i += 256) xs[swz(i)] = state[CORE + i];
    __syncthreads();
    int r = (b - NB1_CORE) * 4 + wave;
    if (r >= SHELL) return;
    float sum = waveReduce(dotRowSw(Wshell + (size_t)r * SHELL, xs, 0, SHELL, lane));
    if (lane == 0) g_pred1[CORE + r] = tanhf(sum);
  } else if (b < NB1_CORE + NB1_SHELL + NB1_WHH) {
    // W_hh @ h: rows are 16B-aligned (H=1024) -> b128 path; raw partial sums.
    float4* xs4 = (float4*)xs;
    const float4* h4 = (const float4*)hin;
    for (int i = tid; i < H / 4; i += 256) xs4[i] = h4[i];
    __syncthreads();
    int r = (b - NB1_CORE - NB1_SHELL) * 4 + wave;  // < 4096 always
    float sum = waveReduce(dotRowAl((const float4*)(Whh + (size_t)r * H), xs4, H / 4, lane));
    if (lane == 0) g_gates[r] = sum;  // biases + W_ih part added in k_gates
  } else {
    // FB: rows 16B-aligned (FB=820, 820%4==0); state+CORE+SHELL is 16B-aligned.
    float4* xs4 = (float4*)xs;
    const float4* f4 = (const float4*)(state + CORE + SHELL);
    for (int i = tid; i < FB / 4; i += 256) xs4[i] = f4[i];
    __syncthreads();
    int r = (b - NB1_CORE - NB1_SHELL - NB1_WHH) * 4 + wave;
    if (r >= FB) return;
    float sum = waveReduce(dotRowAl((const float4*)(Wfb + (size_t)r * FB), xs4, FB / 4, lane));
    if (lane == 0) g_pred1[CORE + SHELL + r] = tanhf(sum);
  }
}

// ---------------- Stage 2: core cross-terms + full s update -----------------
#define NB2_CORE ((CORE + 3) / 4)            // 1229
#define NB2_EW   ((SHELL + FB + 255) / 256)  // 13

__global__ __launch_bounds__(256, 4) void k_stage2(
    const float* __restrict__ state,
    const float* __restrict__ Wsc, const float* __restrict__ Wfc,
    const float* __restrict__ omega, const float* __restrict__ gamma,
    const float* __restrict__ dopamine, float* __restrict__ dout) {
  __shared__ __align__(16) float  xsS[SWZ_SIZE(SHELL)];  // shell preds, swizzled
  __shared__ __align__(16) float4 xsF[FB / 4];           // fb preds, aligned
  float dopa = dopamine[0];
  int b = blockIdx.x, tid = threadIdx.x;
  if (b < NB2_CORE) {
    for (int i = tid; i < SHELL; i += 256) xsS[swz(i)] = g_pred1[CORE + i];
    const float4* f4 = (const float4*)(g_pred1 + CORE + SHELL);  // 7372%4==0
    for (int i = tid; i < FB / 4; i += 256) xsF[i] = f4[i];
    __syncthreads();
    int wave = tid >> 6, lane = tid & 63;
    int r = b * 4 + wave;
    if (r >= CORE) return;
    float d1 = waveReduce(dotRowSw(Wsc + (size_t)r * SHELL, xsS, 0, SHELL, lane));
    float d2 = waveReduce(dotRowAl((const float4*)(Wfc + (size_t)r * FB), xsF, FB / 4, lane));
    if (lane == 0) {
      float pred = g_pred1[r] + tanhf(d1) + tanhf(d2);
      s_update(r, pred, state, omega, gamma, dopa, dout);
    }
  } else {
    int i = CORE + (b - NB2_CORE) * 256 + tid;
    if (i < R_TOT) s_update(i, g_pred1[i], state, omega, gamma, dopa, dout);
  }
}

// ---------------- Stage 3: gates += W_ih @ s + biases -----------------------
__global__ __launch_bounds__(256, 4) void k_gates(
    const float* __restrict__ Wih,
    const float* __restrict__ bih, const float* __restrict__ bhh) {
  __shared__ __align__(16) float4 xs4[R_TOT / 4];  // 32,768 B
  int tid = threadIdx.x;
  const float4* s4 = (const float4*)g_s;
  for (int i = tid; i < R_TOT / 4; i += 256) xs4[i] = s4[i];
  __syncthreads();
  int wave = tid >> 6, lane = tid & 63;
  int r = blockIdx.x * 4 + wave;  // 1024 blocks x 4 waves = 4096 rows
  float sum = waveReduce(dotRowAl((const float4*)(Wih + (size_t)r * R_TOT), xs4, R_TOT / 4, lane));
  if (lane == 0) g_gates[r] += sum + bih[r] + bhh[r];
}

// ---------------- Stage 4: LSTM elementwise + output dot --------------------
__global__ __launch_bounds__(1024) void k_lstm(
    const float* __restrict__ c_in, const float* __restrict__ Wout,
    const float* __restrict__ bout, float* __restrict__ dout) {
  __shared__ float red[16];
  int j = threadIdx.x;
  float ig = g_gates[j], fg = g_gates[H + j], gg = g_gates[2 * H + j], og = g_gates[3 * H + j];
  float c = c_in[j];
  float cn = sigm(fg) * c + sigm(ig) * tanhf(gg);
  float hn = sigm(og) * tanhf(cn);
  dout[1 + R_TOT + j] = hn;
  dout[1 + R_TOT + H + j] = cn;
  float w = Wout[j] * hn;
  w = waveReduce(w);
  int wave = j >> 6, lane = j & 63;
  if (lane == 0) red[wave] = w;
  __syncthreads();
  if (j == 0) {
    float t = 0.f;
    #pragma unroll
    for (int k = 0; k < 16; ++k) t += red[k];
    dout[0] = t + bout[0];
  }
}

extern "C" void kernel_launch(void* const* d_in, const int* in_sizes, int n_in,
                              void* d_out, int out_size, void* d_ws, size_t ws_size,
                              hipStream_t stream) {
  // Map inputs by element-count fingerprint (confirmed f32).
  const float *x = 0, *state = 0, *h = 0, *c = 0, *Win = 0, *Wcore = 0, *Wshell = 0,
              *Wfb = 0, *Wsc = 0, *Wfc = 0, *dopa = 0, *omega = 0, *gamma = 0,
              *Wih = 0, *Whh = 0, *bih = 0, *bhh = 0, *Wout = 0, *bout = 0;
  int n1 = 0, n1024 = 0, n8192 = 0, n4096 = 0;
  for (int i = 0; i < n_in; ++i) {
    const float* p = (const float*)d_in[i];
    switch (in_sizes[i]) {
      case 24157225: Wcore = p; break;            // CORE^2
      case 6036849:  Wshell = p; break;           // SHELL^2
      case 672400:   Wfb = p; break;              // FB^2
      case 12076155: Wsc = p; break;              // CORE*SHELL
      case 4030300:  Wfc = p; break;              // CORE*FB
      case 33554432: Wih = p; break;              // 4H*R
      case 4194304:  Whh = p; break;              // 4H*H
      case 1:    { if (n1 == 0) x = p; else if (n1 == 1) dopa = p; else bout = p; n1++; } break;
      case 1024: { if (n1024 == 0) h = p; else if (n1024 == 1) c = p; else Wout = p; n1024++; } break;
      case 8192: { if (n8192 == 0) state = p; else if (n8192 == 1) Win = p;
                   else if (n8192 == 2) omega = p; else gamma = p; n8192++; } break;
      case 4096: { if (n4096 == 0) bih = p; else bhh = p; n4096++; } break;
      default: break;
    }
  }
  float* dout = (float*)d_out;

  k_stage1<<<NB1_TOT, 256, 0, stream>>>(state, Wcore, Wshell, Wfb, Win, x, Whh, h);
  k_stage2<<<NB2_CORE + NB2_EW, 256, 0, stream>>>(state, Wsc, Wfc, omega, gamma, dopa, dout);
  k_gates<<<(4 * H) / 4, 256, 0, stream>>>(Wih, bih, bhh);
  k_lstm<<<1, 1024, 0, stream>>>(c, Wout, bout, dout);
}